// Round 8
// baseline (88.873 us; speedup 1.0000x reference)
//
#include <hip/hip_runtime.h>

// 8-qubit VQC — closed-form evaluation (math validated R7), single kernel.
// U = Π_j exp(-i θ_j/2 X_{m_j}) (CNOT-folded, all commuting) = H D H;
// <Z_q> = Π_{p∈S_q} cos x_p · Σ_b tab_q[b] Π_{p∈V_q\S_q} (1+(-1)^{b_p} sin x_p),
// tab_q[b] = 2^{-|V_q|} Σ_{S-bits} cos Δ_q  (116 floats, weights-only).
// R8 change vs R7: tab computed PER BLOCK into LDS (threads 0..115, once) —
// no d_ws round-trip (harness re-poisons d_ws with a 41 µs 268 MB fill each
// iteration; R7's table-in-ws chained the kernels behind that fill).

__global__ __launch_bounds__(256) void vqc_kernel(
    const float* __restrict__ inputs,   // (B, 8)
    const float* __restrict__ weights,  // (2, 8)
    float* __restrict__ out)            // (B, 8)
{
    __shared__ float tab[116];

    const int t = threadIdx.x;

    // ---- phase 1: weights-only table into LDS (threads 0..115) ----
    if (t < 116) {
        const int nA[8]      = {2,3,4,5,6,7,8,9};
        const int mofs[8]    = {0,2,5,9,14,20,27,35};
        const int mask_a[44] = {3,5,  3,6,10,  3,6,12,20,  3,6,12,24,40,
                                3,6,12,24,48,80,  3,6,12,24,48,96,160,
                                3,6,12,24,48,96,192,64,  3,6,12,24,48,96,192,128,128};
        const int aidx_a[44] = {0,8,  0,1,9,  0,1,2,10,  0,1,2,3,11,  0,1,2,3,4,12,
                                0,1,2,3,4,5,13,  0,1,2,3,4,5,6,14,  0,1,2,3,4,5,6,7,15};
        const int vmsn[8]    = {2,3,3,4,4,5,4,4};
        const int vmso[8]    = {0,2,5,8,12,16,21,25};
        const int vms_a[29]  = {1,2, 0,2,3, 1,3,4, 0,2,4,5, 1,3,5,6, 0,2,4,6,7, 1,3,5,7, 0,2,4,6};
        const int visn[8]    = {1,1,2,2,3,3,4,4};
        const int viso[8]    = {0,1,2,4,6,9,12,16};
        const int vis_a[20]  = {0, 1, 0,2, 1,3, 0,2,4, 1,3,5, 0,2,4,6, 1,3,5,7};
        const int tofs[9]    = {0,4,12,20,36,52,84,100,116};

        int q = 0;
        while (t >= tofs[q + 1]) ++q;
        const int b = t - tofs[q];

        float wv[16];
#pragma unroll
        for (int j = 0; j < 16; ++j) wv[j] = weights[j];

        int ybase = 0;
        for (int k = 0; k < vmsn[q]; ++k)
            ybase |= ((b >> k) & 1) << vms_a[vmso[q] + k];

        const int nS = 1 << visn[q];
        float acc = 0.0f;
        for (int ys = 0; ys < nS; ++ys) {
            int y = ybase;
            for (int k = 0; k < visn[q]; ++k)
                y |= ((ys >> k) & 1) << vis_a[viso[q] + k];
            float d = 0.0f;
            for (int j = 0; j < nA[q]; ++j) {
                const float th = wv[aidx_a[mofs[q] + j]];
                d += (__popc(y & mask_a[mofs[q] + j]) & 1) ? -th : th;
            }
            acc += __cosf(d);
        }
        tab[t] = acc / (float)(1 << (visn[q] + vmsn[q]));
    }
    __syncthreads();

    // ---- phase 2: per-element closed form ----
    const int e = blockIdx.x * 256 + t;

    const float4* i4 = (const float4*)inputs + (size_t)e * 2;
    const float4 A = i4[0], Bv = i4[1];
    const float x[8] = {A.x, A.y, A.z, A.w, Bv.x, Bv.y, Bv.z, Bv.w};

    float s[8], c[8], ap[8], bm[8];
#pragma unroll
    for (int p = 0; p < 8; ++p) {
        s[p] = __sinf(x[p]);
        c[p] = __cosf(x[p]);
        ap[p] = 1.0f + s[p];
        bm[p] = 1.0f - s[p];
    }

#define EXPAND(dst, src, n, P)                                   \
    _Pragma("unroll") for (int i = 0; i < (n); ++i) {            \
        dst[i] = src[i] * ap[P];                                 \
        dst[i + (n)] = src[i] * bm[P];                           \
    }
#define DOT(G, arr, n, ofs)                                      \
    { float g_ = 0.0f;                                           \
      _Pragma("unroll") for (int i = 0; i < (n); ++i)            \
          g_ = __builtin_fmaf(arr[i], tab[(ofs) + i], g_);       \
      G = g_; }

    // ---- odd chain: bits [1,3,5,7] ----
    float o2[2] = {ap[1], bm[1]};
    float q0p[4];  EXPAND(q0p, o2, 2, 2)        // [1,2]
    float G0;      DOT(G0, q0p, 4, 0)
    float o4[4];   EXPAND(o4, o2, 2, 3)         // [1,3]
    float q2p[8];  EXPAND(q2p, o4, 4, 4)        // [1,3,4]
    float G2;      DOT(G2, q2p, 8, 12)
    float o8[8];   EXPAND(o8, o4, 4, 5)         // [1,3,5]
    float q4p[16]; EXPAND(q4p, o8, 8, 6)        // [1,3,5,6]
    float G4;      DOT(G4, q4p, 16, 36)
    float o16[16]; EXPAND(o16, o8, 8, 7)        // [1,3,5,7]
    float G6;      DOT(G6, o16, 16, 84)

    // ---- even chain: bits [0,2,4,6,7] ----
    float e2[2] = {ap[0], bm[0]};
    float e4[4];   EXPAND(e4, e2, 2, 2)         // [0,2]
    float q1p[8];  EXPAND(q1p, e4, 4, 3)        // [0,2,3]
    float G1;      DOT(G1, q1p, 8, 4)
    float e8[8];   EXPAND(e8, e4, 4, 4)         // [0,2,4]
    float q3p[16]; EXPAND(q3p, e8, 8, 5)        // [0,2,4,5]
    float G3;      DOT(G3, q3p, 16, 20)
    float e16[16]; EXPAND(e16, e8, 8, 6)        // [0,2,4,6]
    float e32[32]; EXPAND(e32, e16, 16, 7)      // [0,2,4,6,7]
    float G5;      DOT(G5, e32, 32, 52)
    float G7;      DOT(G7, e16, 16, 100)

#undef EXPAND
#undef DOT

    // ---- S_q cos prefactors ----
    const float c02 = c[0] * c[2], c024 = c02 * c[4], c0246 = c024 * c[6];
    const float c13 = c[1] * c[3], c135 = c13 * c[5], c1357 = c135 * c[7];

    float4 r0, r1;
    r0.x = c[0]  * G0;  r0.y = c[1]  * G1;  r0.z = c02   * G2;  r0.w = c13   * G3;
    r1.x = c024  * G4;  r1.y = c135  * G5;  r1.z = c0246 * G6;  r1.w = c1357 * G7;

    float4* o4p = (float4*)out + (size_t)e * 2;
    o4p[0] = r0;
    o4p[1] = r1;
}

extern "C" void kernel_launch(void* const* d_in, const int* in_sizes, int n_in,
                              void* d_out, int out_size, void* d_ws, size_t ws_size,
                              hipStream_t stream) {
    const float* inputs  = (const float*)d_in[0];
    const float* weights = (const float*)d_in[1];
    float* out = (float*)d_out;
    const int B = in_sizes[0] / 8;             // 32768
    hipLaunchKernelGGL(vqc_kernel, dim3(B / 256), dim3(256), 0, stream,
                       inputs, weights, out);
}

// Round 9
// 58.620 us; speedup vs baseline: 1.5161x; 1.5161x over previous
//
#include <hip/hip_runtime.h>

// 8-qubit VQC — closed-form evaluation (math validated R7/R8), single kernel.
// <Z_q> = Π_{p∈S_q} cos x_p · Σ_b tab_q[b] Π_{p∈V_q\S_q} (1+(-1)^{b_p} sin x_p)
// tab_q[b] = 2^{-|V_q|} Σ_{S-bits} cos Δ_q  (116 floats, weights-only).
// R9 change vs R8: table phase is FULLY STATIC — per-q template descriptors,
// compile-time loop bounds, constexpr masks/indices folded to immediates.
// R8's runtime-indexed const arrays + dynamic trip counts generated scattered
// memory loads that, at 1 wave/SIMD occupancy, cost ~40 µs of exposed latency.

template<int Q> struct QD;
template<> struct QD<0> { static constexpr int NB=2,NS=1,NA=2;
  static constexpr int vms[2]={1,2}; static constexpr int vis[1]={0};
  static constexpr int mask[2]={3,5}; static constexpr int aidx[2]={0,8}; };
template<> struct QD<1> { static constexpr int NB=3,NS=1,NA=3;
  static constexpr int vms[3]={0,2,3}; static constexpr int vis[1]={1};
  static constexpr int mask[3]={3,6,10}; static constexpr int aidx[3]={0,1,9}; };
template<> struct QD<2> { static constexpr int NB=3,NS=2,NA=4;
  static constexpr int vms[3]={1,3,4}; static constexpr int vis[2]={0,2};
  static constexpr int mask[4]={3,6,12,20}; static constexpr int aidx[4]={0,1,2,10}; };
template<> struct QD<3> { static constexpr int NB=4,NS=2,NA=5;
  static constexpr int vms[4]={0,2,4,5}; static constexpr int vis[2]={1,3};
  static constexpr int mask[5]={3,6,12,24,40}; static constexpr int aidx[5]={0,1,2,3,11}; };
template<> struct QD<4> { static constexpr int NB=4,NS=3,NA=6;
  static constexpr int vms[4]={1,3,5,6}; static constexpr int vis[3]={0,2,4};
  static constexpr int mask[6]={3,6,12,24,48,80}; static constexpr int aidx[6]={0,1,2,3,4,12}; };
template<> struct QD<5> { static constexpr int NB=5,NS=3,NA=7;
  static constexpr int vms[5]={0,2,4,6,7}; static constexpr int vis[3]={1,3,5};
  static constexpr int mask[7]={3,6,12,24,48,96,160}; static constexpr int aidx[7]={0,1,2,3,4,5,13}; };
template<> struct QD<6> { static constexpr int NB=4,NS=4,NA=8;
  static constexpr int vms[4]={1,3,5,7}; static constexpr int vis[4]={0,2,4,6};
  static constexpr int mask[8]={3,6,12,24,48,96,192,64}; static constexpr int aidx[8]={0,1,2,3,4,5,6,14}; };
template<> struct QD<7> { static constexpr int NB=4,NS=4,NA=9;
  static constexpr int vms[4]={0,2,4,6}; static constexpr int vis[4]={1,3,5,7};
  static constexpr int mask[9]={3,6,12,24,48,96,192,128,128}; static constexpr int aidx[9]={0,1,2,3,4,5,6,7,15}; };

template<int Q>
__device__ __forceinline__ float table_entry(int b, const float* wv) {
    using D = QD<Q>;
    int ybase = 0;
#pragma unroll
    for (int k = 0; k < D::NB; ++k) ybase |= ((b >> k) & 1) << D::vms[k];
    float acc = 0.0f;
#pragma unroll
    for (int ys = 0; ys < (1 << D::NS); ++ys) {
        int y = ybase;
#pragma unroll
        for (int k = 0; k < D::NS; ++k) y |= ((ys >> k) & 1) << D::vis[k];
        float d = 0.0f;
#pragma unroll
        for (int j = 0; j < D::NA; ++j)
            d += (__popc(y & D::mask[j]) & 1) ? -wv[D::aidx[j]] : wv[D::aidx[j]];
        acc += __cosf(d);
    }
    return acc * (1.0f / (float)(1 << (D::NS + D::NB)));
}

__global__ __launch_bounds__(256) void vqc_kernel(
    const float* __restrict__ inputs,   // (B, 8)
    const float* __restrict__ weights,  // (2, 8)
    float* __restrict__ out)            // (B, 8)
{
    __shared__ float tab[116];
    const int t = threadIdx.x;

    // ---- phase 1: weights-only table into LDS (threads 0..115, all static) ----
    if (t < 116) {
        float wv[16];
#pragma unroll
        for (int j = 0; j < 16; ++j) wv[j] = weights[j];
        float val;
        if      (t <   4) val = table_entry<0>(t,       wv);
        else if (t <  12) val = table_entry<1>(t -   4, wv);
        else if (t <  20) val = table_entry<2>(t -  12, wv);
        else if (t <  36) val = table_entry<3>(t -  20, wv);
        else if (t <  52) val = table_entry<4>(t -  36, wv);
        else if (t <  84) val = table_entry<5>(t -  52, wv);
        else if (t < 100) val = table_entry<6>(t -  84, wv);
        else              val = table_entry<7>(t - 100, wv);
        tab[t] = val;
    }
    __syncthreads();

    // ---- phase 2: per-element closed form (identical to R8, which passed) ----
    const int e = blockIdx.x * 256 + t;

    const float4* i4 = (const float4*)inputs + (size_t)e * 2;
    const float4 A = i4[0], Bv = i4[1];
    const float x[8] = {A.x, A.y, A.z, A.w, Bv.x, Bv.y, Bv.z, Bv.w};

    float s[8], c[8], ap[8], bm[8];
#pragma unroll
    for (int p = 0; p < 8; ++p) {
        s[p] = __sinf(x[p]);
        c[p] = __cosf(x[p]);
        ap[p] = 1.0f + s[p];
        bm[p] = 1.0f - s[p];
    }

#define EXPAND(dst, src, n, P)                                   \
    _Pragma("unroll") for (int i = 0; i < (n); ++i) {            \
        dst[i] = src[i] * ap[P];                                 \
        dst[i + (n)] = src[i] * bm[P];                           \
    }
#define DOT(G, arr, n, ofs)                                      \
    { float g_ = 0.0f;                                           \
      _Pragma("unroll") for (int i = 0; i < (n); ++i)            \
          g_ = __builtin_fmaf(arr[i], tab[(ofs) + i], g_);       \
      G = g_; }

    // ---- odd chain: bits [1,3,5,7] ----
    float o2[2] = {ap[1], bm[1]};
    float q0p[4];  EXPAND(q0p, o2, 2, 2)        // [1,2]
    float G0;      DOT(G0, q0p, 4, 0)
    float o4[4];   EXPAND(o4, o2, 2, 3)         // [1,3]
    float q2p[8];  EXPAND(q2p, o4, 4, 4)        // [1,3,4]
    float G2;      DOT(G2, q2p, 8, 12)
    float o8[8];   EXPAND(o8, o4, 4, 5)         // [1,3,5]
    float q4p[16]; EXPAND(q4p, o8, 8, 6)        // [1,3,5,6]
    float G4;      DOT(G4, q4p, 16, 36)
    float o16[16]; EXPAND(o16, o8, 8, 7)        // [1,3,5,7]
    float G6;      DOT(G6, o16, 16, 84)

    // ---- even chain: bits [0,2,4,6,7] ----
    float e2[2] = {ap[0], bm[0]};
    float e4[4];   EXPAND(e4, e2, 2, 2)         // [0,2]
    float q1p[8];  EXPAND(q1p, e4, 4, 3)        // [0,2,3]
    float G1;      DOT(G1, q1p, 8, 4)
    float e8[8];   EXPAND(e8, e4, 4, 4)         // [0,2,4]
    float q3p[16]; EXPAND(q3p, e8, 8, 5)        // [0,2,4,5]
    float G3;      DOT(G3, q3p, 16, 20)
    float e16[16]; EXPAND(e16, e8, 8, 6)        // [0,2,4,6]
    float e32[32]; EXPAND(e32, e16, 16, 7)      // [0,2,4,6,7]
    float G5;      DOT(G5, e32, 32, 52)
    float G7;      DOT(G7, e16, 16, 100)

#undef EXPAND
#undef DOT

    // ---- S_q cos prefactors ----
    const float c02 = c[0] * c[2], c024 = c02 * c[4], c0246 = c024 * c[6];
    const float c13 = c[1] * c[3], c135 = c13 * c[5], c1357 = c135 * c[7];

    float4 r0, r1;
    r0.x = c[0]  * G0;  r0.y = c[1]  * G1;  r0.z = c02   * G2;  r0.w = c13   * G3;
    r1.x = c024  * G4;  r1.y = c135  * G5;  r1.z = c0246 * G6;  r1.w = c1357 * G7;

    float4* o4p = (float4*)out + (size_t)e * 2;
    o4p[0] = r0;
    o4p[1] = r1;
}

extern "C" void kernel_launch(void* const* d_in, const int* in_sizes, int n_in,
                              void* d_out, int out_size, void* d_ws, size_t ws_size,
                              hipStream_t stream) {
    const float* inputs  = (const float*)d_in[0];
    const float* weights = (const float*)d_in[1];
    float* out = (float*)d_out;
    const int B = in_sizes[0] / 8;             // 32768
    hipLaunchKernelGGL(vqc_kernel, dim3(B / 256), dim3(256), 0, stream,
                       inputs, weights, out);
}